// Round 1
// baseline (111.487 us; speedup 1.0000x reference)
//
#include <hip/hip_runtime.h>
#include <hip/hip_bf16.h>
#include <math.h>

// ---------------------------------------------------------------------------
// Pipeline:
//  K1 qkv_kernel      : patchify + 3 linear proj (256->8)      [B*N blocks]
//  K2 attn1024        : full softmax attention over N=1024,d=8 [B*N blocks]
//  K3 proj2_kernel    : 3x (8->8) linear                       [2048 thr]
//  K4 attn1024        : second attention
//  K5 init_kernel     : zero the max accumulator
//  K6 head_kernel     : LN(8) + proj(8->3) + bounded softplus + atomic max
//  K7 ksize_kernel    : k = 2*ceil(m)+1 (odd)                  [1 thr]
//  K8 filter_kernel   : bilateral filter, runtime k            [pixel/thr]
// ---------------------------------------------------------------------------

#define B 2
#define N 1024          // 32x32 patches
#define HW 512
#define IMG (HW*HW)     // 262144

__global__ void qkv_kernel(const float* __restrict__ x,
                           const float* __restrict__ Wq, const float* __restrict__ bq,
                           const float* __restrict__ Wk, const float* __restrict__ bk,
                           const float* __restrict__ Wv, const float* __restrict__ bv,
                           float* __restrict__ Q, float* __restrict__ K, float* __restrict__ V) {
    const int bn = blockIdx.x;           // b*1024 + n
    const int b  = bn >> 10;
    const int n  = bn & 1023;
    const int ph = n >> 5, pw = n & 31;
    __shared__ float p[256];
    const int tid = threadIdx.x;
    const int r = tid >> 4, c = tid & 15;
    p[tid] = x[b * IMG + (ph * 16 + r) * HW + pw * 16 + c];
    __syncthreads();
    if (tid < 24) {
        const int mat = tid >> 3, j = tid & 7;
        const float* W  = (mat == 0) ? Wq : (mat == 1) ? Wk : Wv;
        const float* bb = (mat == 0) ? bq : (mat == 1) ? bk : bv;
        float sum = bb[j];
        for (int d = 0; d < 256; ++d) sum += p[d] * W[d * 8 + j];
        float* out = (mat == 0) ? Q : (mat == 1) ? K : V;
        out[bn * 8 + j] = sum;
    }
}

__global__ __launch_bounds__(1024)
void attn1024(const float* __restrict__ Q, const float* __restrict__ K,
              const float* __restrict__ V, float* __restrict__ O) {
    const int bn = blockIdx.x;
    const int b  = bn >> 10;
    const int tid = threadIdx.x;         // 0..1023, one key/value per thread
    const int wave = tid >> 6, lane = tid & 63;
    __shared__ float red[16];
    __shared__ float wred[16][8];

    float qd[8];
#pragma unroll
    for (int d = 0; d < 8; ++d) qd[d] = Q[bn * 8 + d];

    const float* Kr = K + (b << 13) + tid * 8;
    float dot = 0.f;
#pragma unroll
    for (int d = 0; d < 8; ++d) dot += qd[d] * Kr[d];
    dot *= 0.35355339059327373f;         // 8^-0.5

    // block max
    float m = dot;
#pragma unroll
    for (int off = 32; off; off >>= 1) m = fmaxf(m, __shfl_down(m, off));
    if (lane == 0) red[wave] = m;
    __syncthreads();
    if (tid == 0) {
        float mm = red[0];
        for (int i = 1; i < 16; ++i) mm = fmaxf(mm, red[i]);
        red[0] = mm;
    }
    __syncthreads();
    const float mx = red[0];
    __syncthreads();                     // red[] reused below

    const float e = __expf(dot - mx);

    // block sum of e
    float s = e;
#pragma unroll
    for (int off = 32; off; off >>= 1) s += __shfl_down(s, off);
    if (lane == 0) red[wave] = s;

    // weighted V accumulate (wave-level)
    const float* Vr = V + (b << 13) + tid * 8;
    float va[8];
#pragma unroll
    for (int d = 0; d < 8; ++d) {
        float t = e * Vr[d];
#pragma unroll
        for (int off = 32; off; off >>= 1) t += __shfl_down(t, off);
        va[d] = t;
    }
    if (lane == 0) {
#pragma unroll
        for (int d = 0; d < 8; ++d) wred[wave][d] = va[d];
    }
    __syncthreads();
    if (tid == 0) {
        float ss = red[0];
        for (int i = 1; i < 16; ++i) ss += red[i];
        red[0] = ss;
    }
    __syncthreads();
    if (tid < 8) {
        float acc = 0.f;
        for (int i = 0; i < 16; ++i) acc += wred[i][tid];
        O[bn * 8 + tid] = acc / red[0];
    }
}

__global__ void proj2_kernel(const float* __restrict__ F,
                             const float* __restrict__ Wsq, const float* __restrict__ bsq,
                             const float* __restrict__ Wsk, const float* __restrict__ bsk,
                             const float* __restrict__ Wsv, const float* __restrict__ bsv,
                             float* __restrict__ SQ, float* __restrict__ SK, float* __restrict__ SV) {
    const int bn = blockIdx.x * blockDim.x + threadIdx.x;
    if (bn >= B * N) return;
    float f[8];
#pragma unroll
    for (int d = 0; d < 8; ++d) f[d] = F[bn * 8 + d];
#pragma unroll
    for (int j = 0; j < 8; ++j) {
        float a = bsq[j], bb = bsk[j], cc = bsv[j];
#pragma unroll
        for (int d = 0; d < 8; ++d) {
            a  += f[d] * Wsq[d * 8 + j];
            bb += f[d] * Wsk[d * 8 + j];
            cc += f[d] * Wsv[d * 8 + j];
        }
        SQ[bn * 8 + j] = a; SK[bn * 8 + j] = bb; SV[bn * 8 + j] = cc;
    }
}

__global__ void init_kernel(unsigned int* maxbits) { *maxbits = 0u; }

__global__ void head_kernel(const float* __restrict__ F2,
                            const float* __restrict__ g, const float* __restrict__ be,
                            const float* __restrict__ Wp, const float* __restrict__ bp,
                            float* __restrict__ SP, unsigned int* __restrict__ maxbits) {
    const int bn = blockIdx.x * blockDim.x + threadIdx.x;
    if (bn >= B * N) return;
    float f[8];
    float mu = 0.f;
#pragma unroll
    for (int d = 0; d < 8; ++d) { f[d] = F2[bn * 8 + d]; mu += f[d]; }
    mu *= 0.125f;
    float var = 0.f;
#pragma unroll
    for (int d = 0; d < 8; ++d) { float t = f[d] - mu; var += t * t; }
    var *= 0.125f;
    const float inv = rsqrtf(var + 1e-5f);
    float nrm[8];
#pragma unroll
    for (int d = 0; d < 8; ++d) nrm[d] = (f[d] - mu) * inv * g[d] + be[d];
    float mloc = 0.f;
#pragma unroll
    for (int j = 0; j < 3; ++j) {
        float o = bp[j];
#pragma unroll
        for (int d = 0; d < 8; ++d) o += nrm[d] * Wp[d * 3 + j];
        // stable softplus, bounded
        float sp = fmaxf(o, 0.f) + log1pf(__expf(-fabsf(o)));
        float val = fminf(sp, 6.0f) + 1e-6f;
        SP[bn * 3 + j] = val;
        if (j < 2) mloc = fmaxf(mloc, val);
    }
    atomicMax(maxbits, __float_as_uint(mloc));   // positive floats: bit order == value order
}

__global__ void ksize_kernel(const unsigned int* __restrict__ maxbits, int* __restrict__ kint) {
    float m = __uint_as_float(*maxbits);
    int k = 2 * (int)ceilf(m) + 1;
    if ((k & 1) == 0) k += 1;
    if (k < 1) k = 1;
    if (k > 31) k = 31;   // safety (bsp caps at 6 -> k<=15)
    *kint = k;
}

__global__ void filter_kernel(const float* __restrict__ x, const float* __restrict__ SP,
                              const int* __restrict__ kint, float* __restrict__ out) {
    const int id = blockIdx.x * 256 + threadIdx.x;   // b*IMG + h*512 + w
    const int w = id & 511, h = (id >> 9) & 511, b = id >> 18;
    const int kk = *kint, p = kk >> 1;
    const float* xb = x + b * IMG;
    const int patch = (h >> 4) * 32 + (w >> 4);
    const float* sp = SP + (b * N + patch) * 3;
    const float sx = sp[0], sy = sp[1], sr = sp[2];
    const float i2x = 0.5f / (sx * sx);
    const float i2y = 0.5f / (sy * sy);
    const float i2r = 0.5f / (sr * sr);
    const float xc = xb[h * HW + w];
    float acc = 0.f, wsum = 0.f;
    for (int i = 0; i < kk; ++i) {
        int row = h + i - p;
        row = (row < 0) ? -row : ((row > HW - 1) ? 2 * HW - 2 - row : row);
        const float dy = (float)(i - p);
        const float ey = dy * dy * i2y;
        const float* xr = xb + row * HW;
        for (int j = 0; j < kk; ++j) {
            int col = w + j - p;
            col = (col < 0) ? -col : ((col > HW - 1) ? 2 * HW - 2 - col : col);
            const float xv = xr[col];
            const float dx = (float)(j - p);
            const float dd = xc - xv;
            const float wgt = __expf(-(ey + dx * dx * i2x + dd * dd * i2r));
            wsum += wgt;
            acc  += wgt * xv;
        }
    }
    out[id] = acc / (wsum + 1e-8f);
}

extern "C" void kernel_launch(void* const* d_in, const int* in_sizes, int n_in,
                              void* d_out, int out_size, void* d_ws, size_t ws_size,
                              hipStream_t stream) {
    const float* x    = (const float*)d_in[0];
    const float* Wq   = (const float*)d_in[1];
    const float* bq   = (const float*)d_in[2];
    const float* Wk   = (const float*)d_in[3];
    const float* bk   = (const float*)d_in[4];
    const float* Wv   = (const float*)d_in[5];
    const float* bv   = (const float*)d_in[6];
    const float* Wsq  = (const float*)d_in[7];
    const float* bsq  = (const float*)d_in[8];
    const float* Wsk  = (const float*)d_in[9];
    const float* bsk  = (const float*)d_in[10];
    const float* Wsv  = (const float*)d_in[11];
    const float* bsv  = (const float*)d_in[12];
    const float* ln_g = (const float*)d_in[13];
    const float* ln_b = (const float*)d_in[14];
    const float* Wp   = (const float*)d_in[15];
    const float* bp   = (const float*)d_in[16];
    float* out = (float*)d_out;

    float* ws = (float*)d_ws;
    float* Q   = ws;                 // 16384
    float* Kf  = ws + 16384;
    float* Vf  = ws + 32768;
    float* F1  = ws + 49152;
    float* SQ  = ws + 65536;
    float* SK  = ws + 81920;
    float* SV  = ws + 98304;
    float* F2  = ws + 114688;
    float* SP  = ws + 131072;        // 6144
    unsigned int* maxbits = (unsigned int*)(ws + 137216);
    int* kint = (int*)(ws + 137217);

    qkv_kernel<<<B * N, 256, 0, stream>>>(x, Wq, bq, Wk, bk, Wv, bv, Q, Kf, Vf);
    attn1024<<<B * N, 1024, 0, stream>>>(Q, Kf, Vf, F1);
    proj2_kernel<<<(B * N + 255) / 256, 256, 0, stream>>>(F1, Wsq, bsq, Wsk, bsk, Wsv, bsv, SQ, SK, SV);
    attn1024<<<B * N, 1024, 0, stream>>>(SQ, SK, SV, F2);
    init_kernel<<<1, 1, 0, stream>>>(maxbits);
    head_kernel<<<(B * N + 255) / 256, 256, 0, stream>>>(F2, ln_g, ln_b, Wp, bp, SP, maxbits);
    ksize_kernel<<<1, 1, 0, stream>>>(maxbits, kint);
    filter_kernel<<<(B * IMG + 255) / 256, 256, 0, stream>>>(x, SP, kint, out);
}

// Round 2
// 77.116 us; speedup vs baseline: 1.4457x; 1.4457x over previous
//
#include <hip/hip_runtime.h>
#include <hip/hip_bf16.h>
#include <math.h>

// ---------------------------------------------------------------------------
// Pipeline (4 launches):
//  K1 qkv_kernel    : patchify + 3x linear (256->8), zeroes maxbits   [2048 blk]
//  K2 attn_proj     : attention #1 (wave/query) + fused 3x(8->8) proj [512 blk]
//  K3 attn_head     : attention #2 + fused LN + proj(8->3) + bsp + atomicMax
//  K4 filter_kernel : bilateral filter, k specialized at compile time [2048 blk]
// ---------------------------------------------------------------------------

#define B 2
#define N 1024          // 32x32 patches
#define HW 512
#define IMG (HW*HW)

// ---- K1: patchify + QKV projection ---------------------------------------
__global__ __launch_bounds__(256)
void qkv_kernel(const float* __restrict__ x,
                const float* __restrict__ Wq, const float* __restrict__ bq,
                const float* __restrict__ Wk, const float* __restrict__ bk,
                const float* __restrict__ Wv, const float* __restrict__ bv,
                float* __restrict__ Q, float* __restrict__ K, float* __restrict__ V,
                unsigned int* __restrict__ maxbits) {
    const int bn = blockIdx.x;
    const int b  = bn >> 10, n = bn & 1023;
    const int ph = n >> 5, pw = n & 31;
    const int tid = threadIdx.x;
    if (bn == 0 && tid == 0) *maxbits = 0u;   // init for attn_head's atomicMax
    __shared__ float p[256];
    p[tid] = x[b * IMG + (ph * 16 + (tid >> 4)) * HW + pw * 16 + (tid & 15)];
    __syncthreads();
    if (tid < 192) {
        const int out = tid >> 3, sub = tid & 7;   // 24 outputs x 8 partials
        const int mat = out >> 3, j = out & 7;     // wave-uniform mat
        const float* W = (mat == 0) ? Wq : (mat == 1) ? Wk : Wv;
        float sum = 0.f;
#pragma unroll
        for (int dd = 0; dd < 32; ++dd) {
            const int d = dd * 8 + sub;            // lane-consecutive LDS reads
            sum = fmaf(p[d], W[d * 8 + j], sum);
        }
        sum += __shfl_xor(sum, 1);
        sum += __shfl_xor(sum, 2);
        sum += __shfl_xor(sum, 4);
        if (sub == 0) {
            const float* bb = (mat == 0) ? bq : (mat == 1) ? bk : bv;
            float* o = (mat == 0) ? Q : (mat == 1) ? K : V;
            o[bn * 8 + j] = sum + bb[j];
        }
    }
}

// ---- shared attention body: one wave computes one query --------------------
__device__ __forceinline__ void attn_wave(const float* __restrict__ Qp,
                                          const float* __restrict__ Kb,
                                          const float* __restrict__ Vb,
                                          int lane, float f[8]) {
    const float4 q0 = ((const float4*)Qp)[0];
    const float4 q1 = ((const float4*)Qp)[1];
    float dots[16];
    float mx = -3.0e38f;
#pragma unroll
    for (int t = 0; t < 16; ++t) {
        const float4* kr = (const float4*)(Kb + (t * 64 + lane) * 8);
        const float4 k0 = kr[0], k1 = kr[1];
        float d = q0.x * k0.x;
        d = fmaf(q0.y, k0.y, d); d = fmaf(q0.z, k0.z, d); d = fmaf(q0.w, k0.w, d);
        d = fmaf(q1.x, k1.x, d); d = fmaf(q1.y, k1.y, d);
        d = fmaf(q1.z, k1.z, d); d = fmaf(q1.w, k1.w, d);
        d *= 0.35355339059327373f;     // 8^-0.5
        dots[t] = d;
        mx = fmaxf(mx, d);
    }
#pragma unroll
    for (int off = 1; off < 64; off <<= 1) mx = fmaxf(mx, __shfl_xor(mx, off));
    float s = 0.f;
    float va[8] = {0.f, 0.f, 0.f, 0.f, 0.f, 0.f, 0.f, 0.f};
#pragma unroll
    for (int t = 0; t < 16; ++t) {
        const float e = exp2f((dots[t] - mx) * 1.4426950408889634f);
        s += e;
        const float4* vr = (const float4*)(Vb + (t * 64 + lane) * 8);
        const float4 v0 = vr[0], v1 = vr[1];
        va[0] = fmaf(e, v0.x, va[0]); va[1] = fmaf(e, v0.y, va[1]);
        va[2] = fmaf(e, v0.z, va[2]); va[3] = fmaf(e, v0.w, va[3]);
        va[4] = fmaf(e, v1.x, va[4]); va[5] = fmaf(e, v1.y, va[5]);
        va[6] = fmaf(e, v1.z, va[6]); va[7] = fmaf(e, v1.w, va[7]);
    }
#pragma unroll
    for (int off = 1; off < 64; off <<= 1) {
        s += __shfl_xor(s, off);
#pragma unroll
        for (int d2 = 0; d2 < 8; ++d2) va[d2] += __shfl_xor(va[d2], off);
    }
    const float inv = 1.f / s;
#pragma unroll
    for (int d2 = 0; d2 < 8; ++d2) f[d2] = va[d2] * inv;
}

// ---- K2: attention #1 + fused second-stage QKV projection -----------------
__global__ __launch_bounds__(256)
void attn_proj_kernel(const float* __restrict__ Q, const float* __restrict__ K,
                      const float* __restrict__ V,
                      const float* __restrict__ Wsq, const float* __restrict__ bsq,
                      const float* __restrict__ Wsk, const float* __restrict__ bsk,
                      const float* __restrict__ Wsv, const float* __restrict__ bsv,
                      float* __restrict__ SQ, float* __restrict__ SK, float* __restrict__ SV) {
    const int wid = threadIdx.x >> 6, lane = threadIdx.x & 63;
    const int bn = blockIdx.x * 4 + wid, b = bn >> 10;
    float f[8];
    attn_wave(Q + bn * 8, K + (b << 13), V + (b << 13), lane, f);
    if (lane < 24) {
        const int mat = lane >> 3, j = lane & 7;
        const float* W  = (mat == 0) ? Wsq : (mat == 1) ? Wsk : Wsv;
        const float* bb = (mat == 0) ? bsq : (mat == 1) ? bsk : bsv;
        float o = bb[j];
#pragma unroll
        for (int d = 0; d < 8; ++d) o = fmaf(f[d], W[d * 8 + j], o);
        float* op = (mat == 0) ? SQ : (mat == 1) ? SK : SV;
        op[bn * 8 + j] = o;
    }
}

// ---- K3: attention #2 + fused LN + sigma head + global max ----------------
__global__ __launch_bounds__(256)
void attn_head_kernel(const float* __restrict__ SQ, const float* __restrict__ SK,
                      const float* __restrict__ SV,
                      const float* __restrict__ g, const float* __restrict__ be,
                      const float* __restrict__ Wp, const float* __restrict__ bp,
                      float* __restrict__ SP, unsigned int* __restrict__ maxbits) {
    const int wid = threadIdx.x >> 6, lane = threadIdx.x & 63;
    const int bn = blockIdx.x * 4 + wid, b = bn >> 10;
    float f[8];
    attn_wave(SQ + bn * 8, SK + (b << 13), SV + (b << 13), lane, f);
    float mu = 0.f;
#pragma unroll
    for (int d = 0; d < 8; ++d) mu += f[d];
    mu *= 0.125f;
    float var = 0.f;
#pragma unroll
    for (int d = 0; d < 8; ++d) { const float t = f[d] - mu; var = fmaf(t, t, var); }
    var *= 0.125f;
    const float inv = rsqrtf(var + 1e-5f);
    float val = 0.f;
    if (lane < 3) {
        float o = bp[lane];
#pragma unroll
        for (int d = 0; d < 8; ++d) {
            const float nrm = (f[d] - mu) * inv * g[d] + be[d];
            o = fmaf(nrm, Wp[d * 3 + lane], o);
        }
        const float sp = fmaxf(o, 0.f) + log1pf(__expf(-fabsf(o)));
        const float v = fminf(sp, 6.0f) + 1e-6f;
        SP[bn * 3 + lane] = v;
        val = (lane < 2) ? v : 0.f;    // only sx, sy feed the kernel-size max
    }
    float mv = val;
#pragma unroll
    for (int off = 1; off < 64; off <<= 1) mv = fmaxf(mv, __shfl_xor(mv, off));
    if (lane == 0) atomicMax(maxbits, __float_as_uint(mv));
}

// ---- K4: bilateral filter -------------------------------------------------
template<int KK>
__device__ __forceinline__ void filt_spec(const float* __restrict__ xb, int h, int w,
                                          float nix, float niy, float nir,
                                          bool interiorBlk, float* __restrict__ out, int id) {
    constexpr int P = KK / 2;
    float ex[KK];
#pragma unroll
    for (int j = 0; j < KK; ++j) ex[j] = (float)((j - P) * (j - P)) * nix;
    const float xc = xb[h * HW + w];
    float acc0 = 0.f, ws0 = 0.f, acc1 = 0.f, ws1 = 0.f;
    if (interiorBlk) {
        const float* base = xb + (h - P) * HW + (w - P);
#pragma unroll
        for (int i = 0; i < KK; ++i) {
            const float eyr = (float)((i - P) * (i - P)) * niy;
            const float* row = base + i * HW;
#pragma unroll
            for (int j = 0; j < KK; ++j) {
                const float xv = row[j];
                const float dd = xc - xv;
                const float wg = exp2f(fmaf(dd * dd, nir, eyr + ex[j]));
                if (j & 1) { ws1 += wg; acc1 = fmaf(wg, xv, acc1); }
                else       { ws0 += wg; acc0 = fmaf(wg, xv, acc0); }
            }
        }
    } else {
#pragma unroll
        for (int i = 0; i < KK; ++i) {
            int row = h + i - P;
            row = (row < 0) ? -row : ((row > HW - 1) ? 2 * HW - 2 - row : row);
            const float eyr = (float)((i - P) * (i - P)) * niy;
            const float* rp = xb + row * HW;
#pragma unroll
            for (int j = 0; j < KK; ++j) {
                int col = w + j - P;
                col = (col < 0) ? -col : ((col > HW - 1) ? 2 * HW - 2 - col : col);
                const float xv = rp[col];
                const float dd = xc - xv;
                const float wg = exp2f(fmaf(dd * dd, nir, eyr + ex[j]));
                if (j & 1) { ws1 += wg; acc1 = fmaf(wg, xv, acc1); }
                else       { ws0 += wg; acc0 = fmaf(wg, xv, acc0); }
            }
        }
    }
    out[id] = (acc0 + acc1) / (ws0 + ws1 + 1e-8f);
}

__device__ void filt_generic(const float* __restrict__ xb, int h, int w, int kk,
                             float nix, float niy, float nir,
                             float* __restrict__ out, int id) {
    const int P = kk >> 1;
    const float xc = xb[h * HW + w];
    float acc = 0.f, wsum = 0.f;
    for (int i = 0; i < kk; ++i) {
        int row = h + i - P;
        row = (row < 0) ? -row : ((row > HW - 1) ? 2 * HW - 2 - row : row);
        const float eyr = (float)((i - P) * (i - P)) * niy;
        const float* rp = xb + row * HW;
        for (int j = 0; j < kk; ++j) {
            int col = w + j - P;
            col = (col < 0) ? -col : ((col > HW - 1) ? 2 * HW - 2 - col : col);
            const float xv = rp[col];
            const float dd = xc - xv;
            const float wg = exp2f(fmaf(dd * dd, nir, eyr + (float)((j - P) * (j - P)) * nix));
            wsum += wg;
            acc = fmaf(wg, xv, acc);
        }
    }
    out[id] = acc / (wsum + 1e-8f);
}

__global__ __launch_bounds__(256)
void filter_kernel(const float* __restrict__ x, const float* __restrict__ SP,
                   const unsigned int* __restrict__ maxbits, float* __restrict__ out) {
    const int blk = blockIdx.x;
    const int b = blk >> 10, n = blk & 1023;
    const int ph = n >> 5, pw = n & 31;
    const int tid = threadIdx.x;
    const int h = ph * 16 + (tid >> 4), w = pw * 16 + (tid & 15);
    const int id = b * IMG + h * HW + w;
    const float* xb = x + b * IMG;
    const float* sp = SP + (b * N + n) * 3;
    const float sx = sp[0], sy = sp[1], sr = sp[2];
    constexpr float L2E = 1.4426950408889634f;     // fold log2(e) into sigma consts
    const float nix = -0.5f * L2E / (sx * sx);
    const float niy = -0.5f * L2E / (sy * sy);
    const float nir = -0.5f * L2E / (sr * sr);
    const float m = __uint_as_float(*maxbits);
    int kk = 2 * (int)ceilf(m) + 1;                // always odd
    if (kk < 1) kk = 1;
    if (kk > 31) kk = 31;
    const bool ib = (ph > 0) & (ph < 31) & (pw > 0) & (pw < 31);  // window in-bounds for P<=6
    if (kk == 11)      filt_spec<11>(xb, h, w, nix, niy, nir, ib, out, id);
    else if (kk == 9)  filt_spec<9>(xb, h, w, nix, niy, nir, ib, out, id);
    else if (kk == 13) filt_spec<13>(xb, h, w, nix, niy, nir, ib, out, id);
    else               filt_generic(xb, h, w, kk, nix, niy, nir, out, id);
}

extern "C" void kernel_launch(void* const* d_in, const int* in_sizes, int n_in,
                              void* d_out, int out_size, void* d_ws, size_t ws_size,
                              hipStream_t stream) {
    const float* x    = (const float*)d_in[0];
    const float* Wq   = (const float*)d_in[1];
    const float* bq   = (const float*)d_in[2];
    const float* Wk   = (const float*)d_in[3];
    const float* bk   = (const float*)d_in[4];
    const float* Wv   = (const float*)d_in[5];
    const float* bv   = (const float*)d_in[6];
    const float* Wsq  = (const float*)d_in[7];
    const float* bsq  = (const float*)d_in[8];
    const float* Wsk  = (const float*)d_in[9];
    const float* bsk  = (const float*)d_in[10];
    const float* Wsv  = (const float*)d_in[11];
    const float* bsv  = (const float*)d_in[12];
    const float* ln_g = (const float*)d_in[13];
    const float* ln_b = (const float*)d_in[14];
    const float* Wp   = (const float*)d_in[15];
    const float* bp   = (const float*)d_in[16];
    float* out = (float*)d_out;

    float* ws = (float*)d_ws;
    float* Q   = ws;                 // 16384 floats
    float* Kf  = ws + 16384;
    float* Vf  = ws + 32768;
    float* SQ  = ws + 49152;
    float* SK  = ws + 65536;
    float* SV  = ws + 81920;
    float* SP  = ws + 98304;         // 6144 floats
    unsigned int* maxbits = (unsigned int*)(ws + 104448);

    qkv_kernel<<<B * N, 256, 0, stream>>>(x, Wq, bq, Wk, bk, Wv, bv, Q, Kf, Vf, maxbits);
    attn_proj_kernel<<<B * N / 4, 256, 0, stream>>>(Q, Kf, Vf, Wsq, bsq, Wsk, bsk, Wsv, bsv, SQ, SK, SV);
    attn_head_kernel<<<B * N / 4, 256, 0, stream>>>(SQ, SK, SV, ln_g, ln_b, Wp, bp, SP, maxbits);
    filter_kernel<<<B * N, 256, 0, stream>>>(x, SP, maxbits, out);
}